// Round 6
// baseline (1304.826 us; speedup 1.0000x reference)
//
#include <hip/hip_runtime.h>
#include <hip/hip_bf16.h>

#define NB 16
#define NP 4096
#define MS 1024
#define NN 65536
#define FIN 64
#define FOUT 128

typedef __attribute__((ext_vector_type(8))) short short8;
typedef __attribute__((ext_vector_type(4))) float f32x4;

// DPP cumulative-max step (VALU pipe, no LDS)
template <int CTRL>
__device__ __forceinline__ unsigned long long dpp_max_step(unsigned long long k) {
    unsigned lo = (unsigned)k, hi = (unsigned)(k >> 32);
    unsigned plo = (unsigned)__builtin_amdgcn_update_dpp(0, (int)lo, CTRL, 0xf, 0xf, true);
    unsigned phi = (unsigned)__builtin_amdgcn_update_dpp(0, (int)hi, CTRL, 0xf, 0xf, true);
    unsigned long long pk = ((unsigned long long)phi << 32) | plo;   // invalid lanes -> 0 (identity)
    return pk > k ? pk : k;
}

__device__ __forceinline__ unsigned short bf16_rn(float v) {
    unsigned u = __float_as_uint(v);
    unsigned r = u + 0x7FFF + ((u >> 16) & 1);
    return (unsigned short)(r >> 16);
}

// ---------------------------------------------------------------- front: FPS + GEMM + xnorm/split fused
__global__ __launch_bounds__(256, 1) void front_kernel(
        const float* __restrict__ pos, const float* __restrict__ feat,
        const float* __restrict__ W, const float* __restrict__ bias,
        int* __restrict__ fps_idx, float* __restrict__ out_pos, float* __restrict__ out_batch,
        float* __restrict__ xnorm, unsigned short* __restrict__ Xhi, unsigned short* __restrict__ Xlo,
        __hip_bfloat16* __restrict__ hout, float* __restrict__ gsum, float* __restrict__ gsq) {
    __shared__ float smem[13344];
    const int t = threadIdx.x;
    const int b = blockIdx.x;
    if (b < 16) {
        // ---------------- FPS: 256 threads x 16 pts/thread
        float* plds = smem;                                   // 12288 floats
        int* idxL = (int*)(smem + 12288);                     // 1024 ints
        unsigned long long* rk = (unsigned long long*)(smem + 13312);  // 8 u64 (2 parity x 4 waves)
        const float* pb = pos + (size_t)b * NP * 3;
#pragma unroll
        for (int i = 0; i < 48; i++) { int id = t + 256 * i; plds[id] = pb[id]; }
        __syncthreads();
        float px[16], py[16], pz[16], dist[16];
#pragma unroll
        for (int i = 0; i < 16; i++) {
            int p = t + 256 * i;
            px[i] = plds[p * 3 + 0]; py[i] = plds[p * 3 + 1]; pz[i] = plds[p * 3 + 2];
            dist[i] = INFINITY;
        }
        float lx = plds[0], ly = plds[1], lz = plds[2];
        if (t == 0) idxL[0] = 0;
        const int ln = t & 63, wv = t >> 6;   // 4 waves
        for (int m = 1; m < MS; m++) {
#pragma unroll
            for (int i = 0; i < 16; i++) {
                float dx = px[i] - lx, dy = py[i] - ly, dz = pz[i] - lz;
                float d = dx * dx + dy * dy + dz * dz;
                dist[i] = fminf(dist[i], d);
            }
            // in-thread argmax: 4-level tree (pairing keeps index ascending -> ties keep lowest)
            float d1[8]; int i1[8];
#pragma unroll
            for (int i = 0; i < 8; i++) {
                bool g = dist[i + 8] > dist[i];
                d1[i] = g ? dist[i + 8] : dist[i]; i1[i] = g ? (i + 8) : i;
            }
            float d2[4]; int i2[4];
#pragma unroll
            for (int i = 0; i < 4; i++) {
                bool g = d1[i + 4] > d1[i];
                d2[i] = g ? d1[i + 4] : d1[i]; i2[i] = g ? i1[i + 4] : i1[i];
            }
            float d3[2]; int i3[2];
#pragma unroll
            for (int i = 0; i < 2; i++) {
                bool g = d2[i + 2] > d2[i];
                d3[i] = g ? d2[i + 2] : d2[i]; i3[i] = g ? i2[i + 2] : i2[i];
            }
            bool g3 = d3[1] > d3[0];
            float bd = g3 ? d3[1] : d3[0];
            int bi = g3 ? i3[1] : i3[0];
            int bp = t + (bi << 8);
            bd = fmaxf(bd, 0.0f);   // keep packed bits order-preserving
            unsigned long long key =
                ((unsigned long long)__float_as_uint(bd) << 32) | (unsigned)(~bp);
            key = dpp_max_step<0x111>(key);   // row_shr:1
            key = dpp_max_step<0x112>(key);   // row_shr:2
            key = dpp_max_step<0x114>(key);   // row_shr:4
            key = dpp_max_step<0x118>(key);   // row_shr:8
            key = dpp_max_step<0x142>(key);   // row_bcast15
            key = dpp_max_step<0x143>(key);   // row_bcast31
            const int par = (m & 1) * 4;
            if (ln == 63) rk[par + wv] = key;
            __syncthreads();
            unsigned long long k0 = rk[par + 0], k1 = rk[par + 1];
            unsigned long long k2 = rk[par + 2], k3 = rk[par + 3];
            unsigned long long ka = k0 > k1 ? k0 : k1;
            unsigned long long kb = k2 > k3 ? k2 : k3;
            unsigned long long kw = ka > kb ? ka : kb;
            bp = (int)(~(unsigned)kw) & 0xFFF;
            lx = plds[bp * 3 + 0]; ly = plds[bp * 3 + 1]; lz = plds[bp * 3 + 2];
            if (t == 0) idxL[m] = bp;
        }
        __syncthreads();
        for (int m = t; m < MS; m += 256) {
            int ix = idxL[m];
            size_t o = (size_t)b * MS + m;
            fps_idx[o] = ix;
            out_pos[o * 3 + 0] = plds[ix * 3 + 0];
            out_pos[o * 3 + 1] = plds[ix * 3 + 1];
            out_pos[o * 3 + 2] = plds[ix * 3 + 2];
            out_batch[o] = (float)b;
        }
    } else if (b < 272) {
        // ---------------- GEMM + BN stats (rows (b-16)*256 .. +255)
        float* wt = smem;            // [128][68] W^T
        float* fl = smem + 8704;     // [64][68] feature tile
#pragma unroll
        for (int it = 0; it < 8; it++) {
            int lid = t + 256 * it;
            int k = lid >> 5, c4 = lid & 31;
            float4 v = *(const float4*)&W[k * FOUT + c4 * 4];
            wt[(c4 * 4 + 0) * 68 + k] = v.x;
            wt[(c4 * 4 + 1) * 68 + k] = v.y;
            wt[(c4 * 4 + 2) * 68 + k] = v.z;
            wt[(c4 * 4 + 3) * 68 + k] = v.w;
        }
        const int rowbase0 = (b - 16) * 256;
        const int rg = t >> 4, cg = t & 15;
        float sums[8] = {0, 0, 0, 0, 0, 0, 0, 0};
        float sqs[8]  = {0, 0, 0, 0, 0, 0, 0, 0};
        for (int sub = 0; sub < 4; sub++) {
            const int rowbase = rowbase0 + sub * 64;
            __syncthreads();
#pragma unroll
            for (int it = 0; it < 4; it++) {
                int lid = t + 256 * it;
                int r = lid >> 4, f4 = lid & 15;
                float4 v = *(const float4*)&feat[(size_t)(rowbase + r) * FIN + f4 * 4];
                *(float4*)&fl[r * 68 + f4 * 4] = v;
            }
            __syncthreads();
            float acc[4][8];
#pragma unroll
            for (int i = 0; i < 4; i++)
#pragma unroll
                for (int j = 0; j < 8; j++) acc[i][j] = 0.f;
#pragma unroll 2
            for (int k4 = 0; k4 < 16; k4++) {
                float4 f4v[4], w4v[8];
#pragma unroll
                for (int i = 0; i < 4; i++) f4v[i] = *(float4*)&fl[(rg * 4 + i) * 68 + k4 * 4];
#pragma unroll
                for (int j = 0; j < 8; j++) w4v[j] = *(float4*)&wt[(cg + 16 * j) * 68 + k4 * 4];
#pragma unroll
                for (int i = 0; i < 4; i++)
#pragma unroll
                    for (int j = 0; j < 8; j++) {
                        acc[i][j] = fmaf(f4v[i].x, w4v[j].x, acc[i][j]);
                        acc[i][j] = fmaf(f4v[i].y, w4v[j].y, acc[i][j]);
                        acc[i][j] = fmaf(f4v[i].z, w4v[j].z, acc[i][j]);
                        acc[i][j] = fmaf(f4v[i].w, w4v[j].w, acc[i][j]);
                    }
            }
#pragma unroll
            for (int j = 0; j < 8; j++) {
                int c = cg + 16 * j;
                float bc = bias[c];
#pragma unroll
                for (int i = 0; i < 4; i++) {
                    float h = acc[i][j] + bc;
                    sums[j] += h; sqs[j] += h * h;
                    hout[(size_t)(rowbase + rg * 4 + i) * FOUT + c] = __float2bfloat16(h);
                }
            }
        }
        __syncthreads();
        float* suml = fl;
        float* sql  = wt;
#pragma unroll
        for (int j = 0; j < 8; j++) {
            suml[rg * FOUT + cg + 16 * j] = sums[j];
            sql[rg * FOUT + cg + 16 * j]  = sqs[j];
        }
        __syncthreads();
        if (t < FOUT) {
            float S = 0.f, Q = 0.f;
#pragma unroll
            for (int r = 0; r < 16; r++) { S += suml[r * FOUT + t]; Q += sql[r * FOUT + t]; }
            atomicAdd(&gsum[t], S);
            atomicAdd(&gsq[t], Q);
        }
    } else {
        // ---------------- xnorm + bf16 hi/lo split (row per thread)
        int r = (b - 272) * 256 + t;
        const float4* fr = (const float4*)&feat[(size_t)r * FIN];
        unsigned short hrow[64], lrow[64];
        float s = 0.f;
#pragma unroll
        for (int i = 0; i < 16; i++) {
            float4 v = fr[i];
            s += v.x * v.x + v.y * v.y + v.z * v.z + v.w * v.w;
            float vv[4] = {v.x, v.y, v.z, v.w};
#pragma unroll
            for (int j = 0; j < 4; j++) {
                unsigned short h = bf16_rn(vv[j]);
                float hf = __uint_as_float((unsigned)h << 16);
                hrow[4 * i + j] = h;
                lrow[4 * i + j] = bf16_rn(vv[j] - hf);
            }
        }
        xnorm[r] = s;
#pragma unroll
        for (int i = 0; i < 8; i++) {
            short8 hv, lv;
#pragma unroll
            for (int j = 0; j < 8; j++) { hv[j] = (short)hrow[8 * i + j]; lv[j] = (short)lrow[8 * i + j]; }
            *(short8*)&Xhi[(size_t)r * 64 + 8 * i] = hv;
            *(short8*)&Xlo[(size_t)r * 64 + 8 * i] = lv;
        }
    }
}

// ---------------------------------------------------------------- BN finalize
__global__ void finalize_kernel(const float* __restrict__ gsum, const float* __restrict__ gsq,
        const float* __restrict__ gamma, const float* __restrict__ beta,
        float* __restrict__ acoef, float* __restrict__ ccoef) {
    int c = threadIdx.x;
    float mean = gsum[c] * (1.0f / NN);
    float var  = gsq[c] * (1.0f / NN) - mean * mean;
    float s = rsqrtf(var + 1e-5f) * gamma[c];
    acoef[c] = s;
    ccoef[c] = beta[c] - mean * s;
}

// ---------------------------------------------------------------- KNN filter: MFMA bf16 3-pass
// block = 16 queries; wave w owns p-range [w*1024,(w+1)*1024). Each lane dumps its
// per-stream approx top-16 as ushort candidates (union of 16 lists per query = 256
// candidates, guaranteed to contain the exact top-16; refine re-ranks in fp32).
__global__ __launch_bounds__(256, 2) void knn_kernel(
        const unsigned short* __restrict__ Xhi, const unsigned short* __restrict__ Xlo,
        const int* __restrict__ fps_idx, const float* __restrict__ xnorm,
        unsigned short* __restrict__ cand) {
    __shared__ float slds[4][2][16][68];   // per-wave parity score tiles
    const int t = threadIdx.x, b = blockIdx.x;
    const int cloud = b & 15, qt16 = b >> 4;        // qt16 0..63
    const int wave = t >> 6, lane = t & 63;
    const int quad = lane >> 4, col = lane & 15;
    const int cbase = cloud * NP;
    const int qbase = qt16 * 16;

    // A fragments (loop-invariant): rows = fps queries; A[m=lane&15][k=quad*8+j]
    const int qrow = fps_idx[cloud * MS + qbase + col];
    const unsigned short* Qh = Xhi + (size_t)(cbase + qrow) * 64;
    const unsigned short* Ql = Xlo + (size_t)(cbase + qrow) * 64;
    short8 Ah0 = *(const short8*)(Qh + quad * 8);
    short8 Ah1 = *(const short8*)(Qh + 32 + quad * 8);
    short8 Al0 = *(const short8*)(Ql + quad * 8);
    short8 Al1 = *(const short8*)(Ql + 32 + quad * 8);

    float d16[16]; int i16[16];
#pragma unroll
    for (int s = 0; s < 16; s++) { d16[s] = INFINITY; i16[s] = 0; }
    const int ql = lane >> 2, qt = lane & 3;

    for (int ch = 0; ch < 16; ch++) {
        const int pbase = wave * 1024 + ch * 64;
        const int par = ch & 1;
#pragma unroll
        for (int ps = 0; ps < 4; ps++) {
            int prow = cbase + pbase + ps * 16 + col;
            const unsigned short* Bh = Xhi + (size_t)prow * 64;
            const unsigned short* Bl = Xlo + (size_t)prow * 64;
            short8 bh0 = *(const short8*)(Bh + quad * 8);
            short8 bh1 = *(const short8*)(Bh + 32 + quad * 8);
            short8 bl0 = *(const short8*)(Bl + quad * 8);
            short8 bl1 = *(const short8*)(Bl + 32 + quad * 8);
            f32x4 acc = {0.f, 0.f, 0.f, 0.f};
            acc = __builtin_amdgcn_mfma_f32_16x16x32_bf16(Ah0, bh0, acc, 0, 0, 0);
            acc = __builtin_amdgcn_mfma_f32_16x16x32_bf16(Ah1, bh1, acc, 0, 0, 0);
            acc = __builtin_amdgcn_mfma_f32_16x16x32_bf16(Al0, bh0, acc, 0, 0, 0);
            acc = __builtin_amdgcn_mfma_f32_16x16x32_bf16(Al1, bh1, acc, 0, 0, 0);
            acc = __builtin_amdgcn_mfma_f32_16x16x32_bf16(Ah0, bl0, acc, 0, 0, 0);
            acc = __builtin_amdgcn_mfma_f32_16x16x32_bf16(Ah1, bl1, acc, 0, 0, 0);
            float xnv = xnorm[prow];
            // C layout: col(lane&15)=p, row(quad*4+r)=q
#pragma unroll
            for (int r = 0; r < 4; r++) {
                float s = fmaf(-2.0f, acc[r], xnv);
                slds[wave][par][quad * 4 + r][ps * 16 + col] = s;
            }
        }
        // wave-local scan: lane owns (q=ql, p-16th qt); stream = 256 candidates total
#pragma unroll 4
        for (int k = 0; k < 16; k++) {
            float s = slds[wave][par][ql][qt * 16 + k];
            if (s < d16[15]) {
                int gp = pbase + qt * 16 + k;
                bool p_prev, p_cur = true;
#pragma unroll
                for (int x = 15; x >= 1; x--) {
                    p_prev = (s < d16[x - 1]);
                    d16[x] = p_cur ? (p_prev ? d16[x - 1] : s) : d16[x];
                    i16[x] = p_cur ? (p_prev ? i16[x - 1] : gp) : i16[x];
                    p_cur = p_prev;
                }
                if (p_cur) { d16[0] = s; i16[0] = gp; }
            }
        }
    }
    // dump candidate list (no merge; refine re-ranks exactly)
    size_t off = ((size_t)(cloud * MS + qbase + ql)) * 256 + (wave * 4 + qt) * 16;
#pragma unroll
    for (int r = 0; r < 16; r++) cand[off + r] = (unsigned short)i16[r];
}

// ---------------------------------------------------------------- refine: exact fp32 top-16 + gather/BN/ReLU/maxpool
// block = one query; 256 candidate threads.
__global__ __launch_bounds__(256) void refine_kernel(
        const float* __restrict__ feat, const int* __restrict__ fps_idx,
        const float* __restrict__ xnorm, const unsigned short* __restrict__ cand,
        const __hip_bfloat16* __restrict__ h, const float* __restrict__ acoef,
        const float* __restrict__ ccoef, float* __restrict__ out_feat) {
    __shared__ float qlds[64];
    __shared__ float wD[64];
    __shared__ int   wI[64];
    __shared__ int   fIdx[16];
    __shared__ float cf[256];
    const int t = threadIdx.x, b = blockIdx.x;
    const int cloud = b & 15, m = b >> 4;          // cloud <-> XCD locality
    const int q = cloud * MS + m;
    const int cbase = cloud * NP;
    if (t < 128) cf[t] = acoef[t]; else cf[t] = ccoef[t - 128];
    if (t < 16) {
        int qr = fps_idx[q];
        float4 v = ((const float4*)(feat + (size_t)(cbase + qr) * FIN))[t];
        *(float4*)&qlds[t * 4] = v;
    }
    __syncthreads();
    // exact fp32 distance for candidate t
    const int cidx = (int)cand[(size_t)q * 256 + t];
    const float4* xr = (const float4*)(feat + (size_t)(cbase + cidx) * FIN);
    float a0 = 0.f, a1 = 0.f, a2 = 0.f, a3 = 0.f;
#pragma unroll
    for (int i = 0; i < 16; i++) {
        float4 x4 = xr[i];
        a0 = fmaf(qlds[4 * i + 0], x4.x, a0);
        a1 = fmaf(qlds[4 * i + 1], x4.y, a1);
        a2 = fmaf(qlds[4 * i + 2], x4.z, a2);
        a3 = fmaf(qlds[4 * i + 3], x4.w, a3);
    }
    float dot = (a0 + a1) + (a2 + a3);
    float d = fmaf(-2.0f, dot, xnorm[cbase + cidx]);
    // stage 1: wave-local rank count (lex (d, idx) -> stable, matches top_k tie order)
    int rank = 0;
#pragma unroll
    for (int j = 0; j < 64; j++) {
        float dj = __shfl(d, j);
        int ij = __shfl(cidx, j);
        rank += (dj < d || (dj == d && ij < cidx)) ? 1 : 0;
    }
    const int wave = t >> 6;
    if (rank < 16) { wD[wave * 16 + rank] = d; wI[wave * 16 + rank] = cidx; }
    __syncthreads();
    // stage 2: rank among the 64 semifinalists (wave 0)
    if (t < 64) {
        float dv = wD[t]; int iv = wI[t];
        int r2 = 0;
#pragma unroll
        for (int j = 0; j < 64; j++) {
            float dj = __shfl(dv, j);
            int ij = __shfl(iv, j);
            r2 += (dj < dv || (dj == dv && ij < iv)) ? 1 : 0;
        }
        if (r2 < 16) fIdx[r2] = iv;
    }
    __syncthreads();
    // gather + BN affine + relu + maxpool
    if (t < 128) {
        const __hip_bfloat16* hb = h + (size_t)cbase * FOUT;
        const float ac = cf[t], cc = cf[128 + t];
        float mx = -INFINITY;
#pragma unroll
        for (int k = 0; k < 16; k++) {
            int row = fIdx[k];
            float hv = __bfloat162float(hb[(size_t)row * FOUT + t]);
            mx = fmaxf(mx, fmaxf(fmaf(ac, hv, cc), 0.f));
        }
        out_feat[(size_t)q * FOUT + t] = mx;
    }
}

// ---------------------------------------------------------------- launch
extern "C" void kernel_launch(void* const* d_in, const int* in_sizes, int n_in,
                              void* d_out, int out_size, void* d_ws, size_t ws_size,
                              hipStream_t stream) {
    (void)in_sizes; (void)n_in; (void)out_size; (void)ws_size;
    const float* position = (const float*)d_in[0];
    const float* features = (const float*)d_in[1];
    const float* W        = (const float*)d_in[3];
    const float* bias     = (const float*)d_in[4];
    const float* gamma    = (const float*)d_in[5];
    const float* beta     = (const float*)d_in[6];
    float* out = (float*)d_out;

    char* ws = (char*)d_ws;
    int*   fps_idx = (int*)ws;                               // 64 KB
    float* gsum    = (float*)(ws + 65536);                   // 512 B
    float* gsq     = (float*)(ws + 66048);                   // 512 B
    float* acoef   = (float*)(ws + 66560);                   // 512 B
    float* ccoef   = (float*)(ws + 67072);                   // 512 B
    float* xnorm   = (float*)(ws + 67584);                   // 256 KB -> ends 329728
    unsigned short* cand = (unsigned short*)(ws + 329728);   // 8 MB   -> ends 8718336
    unsigned short* Xhi  = (unsigned short*)(ws + 8718336);  // 8 MB   -> ends 17106944
    __hip_bfloat16* hbuf = (__hip_bfloat16*)(ws + 17106944); // 16 MB  -> ends ~33.9 MB

    float* out_feat  = out;                 // [16384][128]
    float* out_pos   = out + 2097152;       // [16384][3]
    float* out_batch = out + 2146304;       // [16384]
    // Stash Xlo in the out_feat region (8 MB exact fit); refine overwrites it afterwards.
    unsigned short* Xlo = (unsigned short*)out;

    hipMemsetAsync(gsum, 0, 1024, stream);  // zero gsum+gsq
    front_kernel<<<528, 256, 0, stream>>>(position, features, W, bias,
                                          fps_idx, out_pos, out_batch, xnorm, Xhi, Xlo,
                                          hbuf, gsum, gsq);
    finalize_kernel<<<1, FOUT, 0, stream>>>(gsum, gsq, gamma, beta, acoef, ccoef);
    knn_kernel<<<1024, 256, 0, stream>>>(Xhi, Xlo, fps_idx, xnorm, cand);
    refine_kernel<<<16384, 256, 0, stream>>>(features, fps_idx, xnorm, cand,
                                             hbuf, acoef, ccoef, out_feat);
}

// Round 7
// 1165.090 us; speedup vs baseline: 1.1199x; 1.1199x over previous
//
#include <hip/hip_runtime.h>
#include <hip/hip_bf16.h>

#define NB 16
#define NP 4096
#define MS 1024
#define NN 65536
#define FIN 64
#define FOUT 128

typedef __attribute__((ext_vector_type(8))) short short8;
typedef __attribute__((ext_vector_type(4))) float f32x4;

// DPP cumulative-max step (VALU pipe, no LDS)
template <int CTRL>
__device__ __forceinline__ unsigned long long dpp_max_step(unsigned long long k) {
    unsigned lo = (unsigned)k, hi = (unsigned)(k >> 32);
    unsigned plo = (unsigned)__builtin_amdgcn_update_dpp(0, (int)lo, CTRL, 0xf, 0xf, true);
    unsigned phi = (unsigned)__builtin_amdgcn_update_dpp(0, (int)hi, CTRL, 0xf, 0xf, true);
    unsigned long long pk = ((unsigned long long)phi << 32) | plo;   // invalid lanes -> 0 (identity)
    return pk > k ? pk : k;
}

__device__ __forceinline__ unsigned short bf16_rn(float v) {
    unsigned u = __float_as_uint(v);
    unsigned r = u + 0x7FFF + ((u >> 16) & 1);
    return (unsigned short)(r >> 16);
}

// ---------------------------------------------------------------- front: FPS + GEMM + xnorm/split fused
__global__ __launch_bounds__(512, 1) void front_kernel(
        const float* __restrict__ pos, const float* __restrict__ feat,
        const float* __restrict__ W, const float* __restrict__ bias,
        int* __restrict__ fps_idx, float* __restrict__ out_pos, float* __restrict__ out_batch,
        float* __restrict__ xnorm, unsigned short* __restrict__ Xhi, unsigned short* __restrict__ Xlo,
        __hip_bfloat16* __restrict__ hout, float* __restrict__ gsum, float* __restrict__ gsq) {
    __shared__ float smem[13344];
    const int t = threadIdx.x;
    const int b = blockIdx.x;
    if (b < 16) {
        // ---------------- FPS: 512 threads x 8 pts/thread (R4-measured best: ~0.63us/step)
        float* plds = smem;                                   // 12288 floats
        int* idxL = (int*)(smem + 12288);                     // 1024 ints
        unsigned long long* rk = (unsigned long long*)(smem + 13312);  // 16 u64
        const float* pb = pos + (size_t)b * NP * 3;
#pragma unroll
        for (int i = 0; i < 24; i++) { int id = t + 512 * i; plds[id] = pb[id]; }
        __syncthreads();
        float px[8], py[8], pz[8], dist[8];
#pragma unroll
        for (int i = 0; i < 8; i++) {
            int p = t + 512 * i;
            px[i] = plds[p * 3 + 0]; py[i] = plds[p * 3 + 1]; pz[i] = plds[p * 3 + 2];
            dist[i] = INFINITY;
        }
        float lx = plds[0], ly = plds[1], lz = plds[2];
        if (t == 0) idxL[0] = 0;
        const int ln = t & 63, wv = t >> 6;   // 8 waves
        for (int m = 1; m < MS; m++) {
#pragma unroll
            for (int i = 0; i < 8; i++) {
                float dx = px[i] - lx, dy = py[i] - ly, dz = pz[i] - lz;
                float d = dx * dx + dy * dy + dz * dz;
                dist[i] = fminf(dist[i], d);
            }
            // in-thread argmax: 3-level tree over 8 (pairing keeps index ascending)
            float d1[4]; int i1[4];
#pragma unroll
            for (int i = 0; i < 4; i++) {
                bool g = dist[i + 4] > dist[i];
                d1[i] = g ? dist[i + 4] : dist[i]; i1[i] = g ? (i + 4) : i;
            }
            float d2[2]; int i2[2];
#pragma unroll
            for (int i = 0; i < 2; i++) {
                bool g = d1[i + 2] > d1[i];
                d2[i] = g ? d1[i + 2] : d1[i]; i2[i] = g ? i1[i + 2] : i1[i];
            }
            bool g3 = d2[1] > d2[0];
            float bd = g3 ? d2[1] : d2[0];
            int bi = g3 ? i2[1] : i2[0];
            int bp = t + (bi << 9);
            unsigned long long key =
                ((unsigned long long)__float_as_uint(bd) << 32) | (unsigned)(~bp);
            key = dpp_max_step<0x111>(key);   // row_shr:1
            key = dpp_max_step<0x112>(key);   // row_shr:2
            key = dpp_max_step<0x114>(key);   // row_shr:4
            key = dpp_max_step<0x118>(key);   // row_shr:8
            key = dpp_max_step<0x142>(key);   // row_bcast15
            key = dpp_max_step<0x143>(key);   // row_bcast31
            const int par = (m & 1) * 8;
            if (ln == 63) rk[par + wv] = key;
            __syncthreads();
            unsigned long long k0 = rk[par + 0], k1 = rk[par + 1];
            unsigned long long k2 = rk[par + 2], k3 = rk[par + 3];
            unsigned long long k4 = rk[par + 4], k5 = rk[par + 5];
            unsigned long long k6 = rk[par + 6], k7 = rk[par + 7];
            unsigned long long ka = k0 > k1 ? k0 : k1;
            unsigned long long kb = k2 > k3 ? k2 : k3;
            unsigned long long kc = k4 > k5 ? k4 : k5;
            unsigned long long kd = k6 > k7 ? k6 : k7;
            ka = ka > kb ? ka : kb;
            kc = kc > kd ? kc : kd;
            unsigned long long kw = ka > kc ? ka : kc;
            bp = (int)(~(unsigned)kw) & 0xFFF;
            lx = plds[bp * 3 + 0]; ly = plds[bp * 3 + 1]; lz = plds[bp * 3 + 2];
            if (t == 0) idxL[m] = bp;
        }
        __syncthreads();
        for (int m = t; m < MS; m += 512) {
            int ix = idxL[m];
            size_t o = (size_t)b * MS + m;
            fps_idx[o] = ix;
            out_pos[o * 3 + 0] = plds[ix * 3 + 0];
            out_pos[o * 3 + 1] = plds[ix * 3 + 1];
            out_pos[o * 3 + 2] = plds[ix * 3 + 2];
            out_batch[o] = (float)b;
        }
    } else if (b < 272) {
        // ---------------- GEMM + BN stats (rows (b-16)*256 .. +255), 512 threads
        float* wt = smem;            // [128][68] W^T
        float* fl = smem + 8704;     // [64][68] feature tile
#pragma unroll
        for (int it = 0; it < 4; it++) {               // stage W -> wt (transposed)
            int lid = t + 512 * it;                    // 2048 float4s
            int k = lid >> 5, c4 = lid & 31;
            float4 v = *(const float4*)&W[k * FOUT + c4 * 4];
            wt[(c4 * 4 + 0) * 68 + k] = v.x;
            wt[(c4 * 4 + 1) * 68 + k] = v.y;
            wt[(c4 * 4 + 2) * 68 + k] = v.z;
            wt[(c4 * 4 + 3) * 68 + k] = v.w;
        }
        const int rowbase0 = (b - 16) * 256;
        const int rg = t >> 5, cg = t & 31;
        float sums[4] = {0, 0, 0, 0};
        float sqs[4]  = {0, 0, 0, 0};
        for (int sub = 0; sub < 4; sub++) {
            const int rowbase = rowbase0 + sub * 64;
            __syncthreads();
#pragma unroll
            for (int it = 0; it < 2; it++) {           // stage 64 feature rows
                int lid = t + 512 * it;
                int r = lid >> 4, f4 = lid & 15;
                float4 v = *(const float4*)&feat[(size_t)(rowbase + r) * FIN + f4 * 4];
                *(float4*)&fl[r * 68 + f4 * 4] = v;
            }
            __syncthreads();
            float acc[4][4];
#pragma unroll
            for (int i = 0; i < 4; i++)
#pragma unroll
                for (int j = 0; j < 4; j++) acc[i][j] = 0.f;
#pragma unroll 2
            for (int k4 = 0; k4 < 16; k4++) {
                float4 f4v[4], w4v[4];
#pragma unroll
                for (int i = 0; i < 4; i++) f4v[i] = *(float4*)&fl[(rg * 4 + i) * 68 + k4 * 4];
#pragma unroll
                for (int j = 0; j < 4; j++) w4v[j] = *(float4*)&wt[(cg + 32 * j) * 68 + k4 * 4];
#pragma unroll
                for (int i = 0; i < 4; i++)
#pragma unroll
                    for (int j = 0; j < 4; j++) {
                        acc[i][j] = fmaf(f4v[i].x, w4v[j].x, acc[i][j]);
                        acc[i][j] = fmaf(f4v[i].y, w4v[j].y, acc[i][j]);
                        acc[i][j] = fmaf(f4v[i].z, w4v[j].z, acc[i][j]);
                        acc[i][j] = fmaf(f4v[i].w, w4v[j].w, acc[i][j]);
                    }
            }
#pragma unroll
            for (int j = 0; j < 4; j++) {
                int c = cg + 32 * j;
                float bc = bias[c];
#pragma unroll
                for (int i = 0; i < 4; i++) {
                    float h = acc[i][j] + bc;
                    sums[j] += h; sqs[j] += h * h;
                    hout[(size_t)(rowbase + rg * 4 + i) * FOUT + c] = __float2bfloat16(h);
                }
            }
        }
        __syncthreads();
        float* suml = fl;   // 16*128 = 2048 floats
        float* sql  = wt;
#pragma unroll
        for (int j = 0; j < 4; j++) {
            suml[rg * FOUT + cg + 32 * j] = sums[j];
            sql[rg * FOUT + cg + 32 * j]  = sqs[j];
        }
        __syncthreads();
        if (t < FOUT) {
            float S = 0.f, Q = 0.f;
#pragma unroll
            for (int r = 0; r < 16; r++) { S += suml[r * FOUT + t]; Q += sql[r * FOUT + t]; }
            atomicAdd(&gsum[t], S);
            atomicAdd(&gsq[t], Q);
        }
    } else {
        // ---------------- xnorm + bf16 hi/lo split (512 threads, 128 blocks)
        int r = (b - 272) * 512 + t;
        const float4* fr = (const float4*)&feat[(size_t)r * FIN];
        unsigned short hrow[64], lrow[64];
        float s = 0.f;
#pragma unroll
        for (int i = 0; i < 16; i++) {
            float4 v = fr[i];
            s += v.x * v.x + v.y * v.y + v.z * v.z + v.w * v.w;
            float vv[4] = {v.x, v.y, v.z, v.w};
#pragma unroll
            for (int j = 0; j < 4; j++) {
                unsigned short h = bf16_rn(vv[j]);
                float hf = __uint_as_float((unsigned)h << 16);
                hrow[4 * i + j] = h;
                lrow[4 * i + j] = bf16_rn(vv[j] - hf);
            }
        }
        xnorm[r] = s;
#pragma unroll
        for (int i = 0; i < 8; i++) {
            short8 hv, lv;
#pragma unroll
            for (int j = 0; j < 8; j++) { hv[j] = (short)hrow[8 * i + j]; lv[j] = (short)lrow[8 * i + j]; }
            *(short8*)&Xhi[(size_t)r * 64 + 8 * i] = hv;
            *(short8*)&Xlo[(size_t)r * 64 + 8 * i] = lv;
        }
    }
}

// ---------------------------------------------------------------- BN finalize
__global__ void finalize_kernel(const float* __restrict__ gsum, const float* __restrict__ gsq,
        const float* __restrict__ gamma, const float* __restrict__ beta,
        float* __restrict__ acoef, float* __restrict__ ccoef) {
    int c = threadIdx.x;
    float mean = gsum[c] * (1.0f / NN);
    float var  = gsq[c] * (1.0f / NN) - mean * mean;
    float s = rsqrtf(var + 1e-5f) * gamma[c];
    acoef[c] = s;
    ccoef[c] = beta[c] - mean * s;
}

// ---------------------------------------------------------------- KNN filter: MFMA bf16, wave = 16q x 2048p
// grid 512: cloud(16) x qgroup(16, 64 q each) x half(2). Wave w owns queries w*16..w*16+15.
// Lane stream = (q, p mod 4 partition) over 128 tiles -> 512 candidates; per-stream top-16
// union (4 streams x 2 halves = 128/query) provably contains the exact top-16.
__global__ __launch_bounds__(256, 2) void knn_kernel(
        const unsigned short* __restrict__ Xhi, const unsigned short* __restrict__ Xlo,
        const int* __restrict__ fps_idx, const float* __restrict__ xnorm,
        unsigned short* __restrict__ cand) {
    __shared__ float slds[4][16][17];   // per-wave 16q x 16p score tile (padded, no barriers)
    const int t = threadIdx.x, b = blockIdx.x;
    const int cloud = b & 15, qg = (b >> 4) & 15, half = b >> 8;
    const int wave = t >> 6, lane = t & 63;
    const int quad = lane >> 4, col = lane & 15;
    const int cbase = cloud * NP;
    const int qloc = qg * 64 + wave * 16;

    // A fragments (loop-invariant): A[m=lane&15][k=quad*8+j]
    const int qrow = fps_idx[cloud * MS + qloc + col];
    const unsigned short* Qh = Xhi + (size_t)(cbase + qrow) * 64;
    const unsigned short* Ql = Xlo + (size_t)(cbase + qrow) * 64;
    short8 Ah0 = *(const short8*)(Qh + quad * 8);
    short8 Ah1 = *(const short8*)(Qh + 32 + quad * 8);
    short8 Al0 = *(const short8*)(Ql + quad * 8);
    short8 Al1 = *(const short8*)(Ql + 32 + quad * 8);

    float d16[16]; int i16[16];
#pragma unroll
    for (int s = 0; s < 16; s++) { d16[s] = INFINITY; i16[s] = 0; }
    const int ql = lane >> 2, qt = lane & 3;
    const int pstart = half * 2048;

    for (int tile = 0; tile < 128; tile++) {
        const int pb = pstart + tile * 16;
        const int prow = cbase + pb + col;
        const unsigned short* Bh = Xhi + (size_t)prow * 64;
        const unsigned short* Bl = Xlo + (size_t)prow * 64;
        short8 bh0 = *(const short8*)(Bh + quad * 8);
        short8 bh1 = *(const short8*)(Bh + 32 + quad * 8);
        short8 bl0 = *(const short8*)(Bl + quad * 8);
        short8 bl1 = *(const short8*)(Bl + 32 + quad * 8);
        f32x4 acc = {0.f, 0.f, 0.f, 0.f};
        acc = __builtin_amdgcn_mfma_f32_16x16x32_bf16(Ah0, bh0, acc, 0, 0, 0);
        acc = __builtin_amdgcn_mfma_f32_16x16x32_bf16(Ah1, bh1, acc, 0, 0, 0);
        acc = __builtin_amdgcn_mfma_f32_16x16x32_bf16(Al0, bh0, acc, 0, 0, 0);
        acc = __builtin_amdgcn_mfma_f32_16x16x32_bf16(Al1, bh1, acc, 0, 0, 0);
        acc = __builtin_amdgcn_mfma_f32_16x16x32_bf16(Ah0, bl0, acc, 0, 0, 0);
        acc = __builtin_amdgcn_mfma_f32_16x16x32_bf16(Ah1, bl1, acc, 0, 0, 0);
        float xnv = xnorm[prow];
        // C layout: col(lane&15)=p, row(quad*4+r)=q  (validated R6)
#pragma unroll
        for (int r = 0; r < 4; r++)
            slds[wave][quad * 4 + r][col] = fmaf(-2.0f, acc[r], xnv);
        // same-wave LDS write->read (compiler inserts lgkmcnt; pattern validated R6)
#pragma unroll
        for (int k = 0; k < 4; k++) {
            float s = slds[wave][ql][qt * 4 + k];
            if (s < d16[15]) {
                int gp = pb + qt * 4 + k;
                bool p_prev, p_cur = true;
#pragma unroll
                for (int x = 15; x >= 1; x--) {
                    p_prev = (s < d16[x - 1]);
                    d16[x] = p_cur ? (p_prev ? d16[x - 1] : s) : d16[x];
                    i16[x] = p_cur ? (p_prev ? i16[x - 1] : gp) : i16[x];
                    p_cur = p_prev;
                }
                if (p_cur) { d16[0] = s; i16[0] = gp; }
            }
        }
    }
    const int qidx = cloud * MS + qloc + ql;
    size_t off = (size_t)qidx * 128 + half * 64 + qt * 16;
#pragma unroll
    for (int r = 0; r < 16; r++) cand[off + r] = (unsigned short)i16[r];
}

// ---------------------------------------------------------------- refine: exact fp32 top-16 + gather/BN/ReLU/maxpool
// block = one query; 128 candidates, 2 lanes/candidate.
__global__ __launch_bounds__(256) void refine_kernel(
        const float* __restrict__ feat, const int* __restrict__ fps_idx,
        const float* __restrict__ xnorm, const unsigned short* __restrict__ cand,
        const __hip_bfloat16* __restrict__ h, const float* __restrict__ acoef,
        const float* __restrict__ ccoef, float* __restrict__ out_feat) {
    __shared__ float qlds[64];
    __shared__ float cD[128];
    __shared__ int   cI[128];
    __shared__ int   fIdx[16];
    __shared__ float cf[256];
    const int t = threadIdx.x, b = blockIdx.x;
    const int cloud = b & 15, m = b >> 4;          // cloud <-> XCD locality
    const int q = cloud * MS + m;
    const int cbase = cloud * NP;
    if (t < 128) cf[t] = acoef[t]; else cf[t] = ccoef[t - 128];
    if (t < 16) {
        int qr = fps_idx[q];
        float4 v = ((const float4*)(feat + (size_t)(cbase + qr) * FIN))[t];
        *(float4*)&qlds[t * 4] = v;
    }
    __syncthreads();
    // exact fp32 distance: candidate c = t>>1, half jh = t&1 covers 32 dims (64B contiguous)
    const int c = t >> 1, jh = t & 1;
    const int cidx = (int)cand[(size_t)q * 128 + c];
    const float4* xr = (const float4*)(feat + (size_t)(cbase + cidx) * FIN) + jh * 8;
    float a0 = 0.f, a1 = 0.f, a2 = 0.f, a3 = 0.f;
#pragma unroll
    for (int i = 0; i < 8; i++) {
        float4 x4 = xr[i];
        a0 = fmaf(qlds[jh * 32 + 4 * i + 0], x4.x, a0);
        a1 = fmaf(qlds[jh * 32 + 4 * i + 1], x4.y, a1);
        a2 = fmaf(qlds[jh * 32 + 4 * i + 2], x4.z, a2);
        a3 = fmaf(qlds[jh * 32 + 4 * i + 3], x4.w, a3);
    }
    float a = (a0 + a1) + (a2 + a3);
    a += __shfl_xor(a, 1);
    if (jh == 0) {
        cD[c] = fmaf(-2.0f, a, xnorm[cbase + cidx]);
        cI[c] = cidx;
    }
    __syncthreads();
    // rank-count among 128 (lex (d, idx); candidates are distinct by construction)
    if (t < 128) {
        float dv = cD[t]; int iv = cI[t]; int rank = 0;
#pragma unroll 8
        for (int j = 0; j < 128; j++) {
            float dj = cD[j]; int ij = cI[j];
            rank += (dj < dv || (dj == dv && ij < iv)) ? 1 : 0;
        }
        if (rank < 16) fIdx[rank] = iv;
    }
    __syncthreads();
    // gather + BN affine + relu + maxpool
    if (t < 128) {
        const __hip_bfloat16* hb = h + (size_t)cbase * FOUT;
        const float ac = cf[t], cc = cf[128 + t];
        float mx = -INFINITY;
#pragma unroll
        for (int k = 0; k < 16; k++) {
            int row = fIdx[k];
            float hv = __bfloat162float(hb[(size_t)row * FOUT + t]);
            mx = fmaxf(mx, fmaxf(fmaf(ac, hv, cc), 0.f));
        }
        out_feat[(size_t)q * FOUT + t] = mx;
    }
}

// ---------------------------------------------------------------- launch
extern "C" void kernel_launch(void* const* d_in, const int* in_sizes, int n_in,
                              void* d_out, int out_size, void* d_ws, size_t ws_size,
                              hipStream_t stream) {
    (void)in_sizes; (void)n_in; (void)out_size; (void)ws_size;
    const float* position = (const float*)d_in[0];
    const float* features = (const float*)d_in[1];
    const float* W        = (const float*)d_in[3];
    const float* bias     = (const float*)d_in[4];
    const float* gamma    = (const float*)d_in[5];
    const float* beta     = (const float*)d_in[6];
    float* out = (float*)d_out;

    char* ws = (char*)d_ws;
    int*   fps_idx = (int*)ws;                               // 64 KB
    float* gsum    = (float*)(ws + 65536);                   // 512 B
    float* gsq     = (float*)(ws + 66048);                   // 512 B
    float* acoef   = (float*)(ws + 66560);                   // 512 B
    float* ccoef   = (float*)(ws + 67072);                   // 512 B
    float* xnorm   = (float*)(ws + 67584);                   // 256 KB -> ends 329728
    unsigned short* cand = (unsigned short*)(ws + 329728);   // 4 MB   -> ends 4524032
    unsigned short* Xhi  = (unsigned short*)(ws + 4524032);  // 8 MB   -> ends 12912640
    __hip_bfloat16* hbuf = (__hip_bfloat16*)(ws + 12912640); // 16 MB  -> ends ~29.7 MB

    float* out_feat  = out;                 // [16384][128]
    float* out_pos   = out + 2097152;       // [16384][3]
    float* out_batch = out + 2146304;       // [16384]
    // Stash Xlo in the out_feat region (8 MB exact fit); refine overwrites it afterwards.
    unsigned short* Xlo = (unsigned short*)out;

    hipMemsetAsync(gsum, 0, 1024, stream);  // zero gsum+gsq
    front_kernel<<<400, 512, 0, stream>>>(position, features, W, bias,
                                          fps_idx, out_pos, out_batch, xnorm, Xhi, Xlo,
                                          hbuf, gsum, gsq);
    finalize_kernel<<<1, FOUT, 0, stream>>>(gsum, gsq, gamma, beta, acoef, ccoef);
    knn_kernel<<<512, 256, 0, stream>>>(Xhi, Xlo, fps_idx, xnorm, cand);
    refine_kernel<<<16384, 256, 0, stream>>>(features, fps_idx, xnorm, cand,
                                             hbuf, acoef, ccoef, out_feat);
}

// Round 8
// 1071.037 us; speedup vs baseline: 1.2183x; 1.0878x over previous
//
#include <hip/hip_runtime.h>
#include <hip/hip_bf16.h>

#define NB 16
#define NP 4096
#define MS 1024
#define NN 65536
#define FIN 64
#define FOUT 128
#define KNN_MARGIN 0.25f

typedef __attribute__((ext_vector_type(8))) short short8;
typedef __attribute__((ext_vector_type(4))) float f32x4;

// DPP cumulative-max step (VALU pipe, no LDS)
template <int CTRL>
__device__ __forceinline__ unsigned long long dpp_max_step(unsigned long long k) {
    unsigned lo = (unsigned)k, hi = (unsigned)(k >> 32);
    unsigned plo = (unsigned)__builtin_amdgcn_update_dpp(0, (int)lo, CTRL, 0xf, 0xf, true);
    unsigned phi = (unsigned)__builtin_amdgcn_update_dpp(0, (int)hi, CTRL, 0xf, 0xf, true);
    unsigned long long pk = ((unsigned long long)phi << 32) | plo;   // invalid lanes -> 0 (identity)
    return pk > k ? pk : k;
}

__device__ __forceinline__ unsigned short bf16_rn(float v) {
    unsigned u = __float_as_uint(v);
    unsigned r = u + 0x7FFF + ((u >> 16) & 1);
    return (unsigned short)(r >> 16);
}

// ---------------------------------------------------------------- front: FPS + GEMM + xnorm/split fused
__global__ __launch_bounds__(512, 1) void front_kernel(
        const float* __restrict__ pos, const float* __restrict__ feat,
        const float* __restrict__ W, const float* __restrict__ bias,
        int* __restrict__ fps_idx, float* __restrict__ out_pos, float* __restrict__ out_batch,
        float* __restrict__ xnorm, unsigned short* __restrict__ Xhi, unsigned short* __restrict__ Xlo,
        __hip_bfloat16* __restrict__ hout, float* __restrict__ gsum, float* __restrict__ gsq) {
    __shared__ float smem[13344];
    const int t = threadIdx.x;
    const int b = blockIdx.x;
    if (b < 16) {
        // ---------------- FPS: 512 threads x 8 pts/thread (R4/R7-measured best)
        float* plds = smem;                                   // 12288 floats
        int* idxL = (int*)(smem + 12288);                     // 1024 ints
        unsigned long long* rk = (unsigned long long*)(smem + 13312);  // 16 u64
        const float* pb = pos + (size_t)b * NP * 3;
#pragma unroll
        for (int i = 0; i < 24; i++) { int id = t + 512 * i; plds[id] = pb[id]; }
        __syncthreads();
        float px[8], py[8], pz[8], dist[8];
#pragma unroll
        for (int i = 0; i < 8; i++) {
            int p = t + 512 * i;
            px[i] = plds[p * 3 + 0]; py[i] = plds[p * 3 + 1]; pz[i] = plds[p * 3 + 2];
            dist[i] = INFINITY;
        }
        float lx = plds[0], ly = plds[1], lz = plds[2];
        if (t == 0) idxL[0] = 0;
        const int ln = t & 63, wv = t >> 6;   // 8 waves
        for (int m = 1; m < MS; m++) {
#pragma unroll
            for (int i = 0; i < 8; i++) {
                float dx = px[i] - lx, dy = py[i] - ly, dz = pz[i] - lz;
                float d = dx * dx + dy * dy + dz * dz;
                dist[i] = fminf(dist[i], d);
            }
            float d1[4]; int i1[4];
#pragma unroll
            for (int i = 0; i < 4; i++) {
                bool g = dist[i + 4] > dist[i];
                d1[i] = g ? dist[i + 4] : dist[i]; i1[i] = g ? (i + 4) : i;
            }
            float d2[2]; int i2[2];
#pragma unroll
            for (int i = 0; i < 2; i++) {
                bool g = d1[i + 2] > d1[i];
                d2[i] = g ? d1[i + 2] : d1[i]; i2[i] = g ? i1[i + 2] : i1[i];
            }
            bool g3 = d2[1] > d2[0];
            float bd = g3 ? d2[1] : d2[0];
            int bi = g3 ? i2[1] : i2[0];
            int bp = t + (bi << 9);
            unsigned long long key =
                ((unsigned long long)__float_as_uint(bd) << 32) | (unsigned)(~bp);
            key = dpp_max_step<0x111>(key);   // row_shr:1
            key = dpp_max_step<0x112>(key);   // row_shr:2
            key = dpp_max_step<0x114>(key);   // row_shr:4
            key = dpp_max_step<0x118>(key);   // row_shr:8
            key = dpp_max_step<0x142>(key);   // row_bcast15
            key = dpp_max_step<0x143>(key);   // row_bcast31
            const int par = (m & 1) * 8;
            if (ln == 63) rk[par + wv] = key;
            __syncthreads();
            unsigned long long k0 = rk[par + 0], k1 = rk[par + 1];
            unsigned long long k2 = rk[par + 2], k3 = rk[par + 3];
            unsigned long long k4 = rk[par + 4], k5 = rk[par + 5];
            unsigned long long k6 = rk[par + 6], k7 = rk[par + 7];
            unsigned long long ka = k0 > k1 ? k0 : k1;
            unsigned long long kb = k2 > k3 ? k2 : k3;
            unsigned long long kc = k4 > k5 ? k4 : k5;
            unsigned long long kd = k6 > k7 ? k6 : k7;
            ka = ka > kb ? ka : kb;
            kc = kc > kd ? kc : kd;
            unsigned long long kw = ka > kc ? ka : kc;
            bp = (int)(~(unsigned)kw) & 0xFFF;
            lx = plds[bp * 3 + 0]; ly = plds[bp * 3 + 1]; lz = plds[bp * 3 + 2];
            if (t == 0) idxL[m] = bp;
        }
        __syncthreads();
        for (int m = t; m < MS; m += 512) {
            int ix = idxL[m];
            size_t o = (size_t)b * MS + m;
            fps_idx[o] = ix;
            out_pos[o * 3 + 0] = plds[ix * 3 + 0];
            out_pos[o * 3 + 1] = plds[ix * 3 + 1];
            out_pos[o * 3 + 2] = plds[ix * 3 + 2];
            out_batch[o] = (float)b;
        }
    } else if (b < 272) {
        // ---------------- GEMM + BN stats (rows (b-16)*256 .. +255), 512 threads
        float* wt = smem;            // [128][68] W^T
        float* fl = smem + 8704;     // [64][68] feature tile
#pragma unroll
        for (int it = 0; it < 4; it++) {
            int lid = t + 512 * it;
            int k = lid >> 5, c4 = lid & 31;
            float4 v = *(const float4*)&W[k * FOUT + c4 * 4];
            wt[(c4 * 4 + 0) * 68 + k] = v.x;
            wt[(c4 * 4 + 1) * 68 + k] = v.y;
            wt[(c4 * 4 + 2) * 68 + k] = v.z;
            wt[(c4 * 4 + 3) * 68 + k] = v.w;
        }
        const int rowbase0 = (b - 16) * 256;
        const int rg = t >> 5, cg = t & 31;
        float sums[4] = {0, 0, 0, 0};
        float sqs[4]  = {0, 0, 0, 0};
        for (int sub = 0; sub < 4; sub++) {
            const int rowbase = rowbase0 + sub * 64;
            __syncthreads();
#pragma unroll
            for (int it = 0; it < 2; it++) {
                int lid = t + 512 * it;
                int r = lid >> 4, f4 = lid & 15;
                float4 v = *(const float4*)&feat[(size_t)(rowbase + r) * FIN + f4 * 4];
                *(float4*)&fl[r * 68 + f4 * 4] = v;
            }
            __syncthreads();
            float acc[4][4];
#pragma unroll
            for (int i = 0; i < 4; i++)
#pragma unroll
                for (int j = 0; j < 4; j++) acc[i][j] = 0.f;
#pragma unroll 2
            for (int k4 = 0; k4 < 16; k4++) {
                float4 f4v[4], w4v[4];
#pragma unroll
                for (int i = 0; i < 4; i++) f4v[i] = *(float4*)&fl[(rg * 4 + i) * 68 + k4 * 4];
#pragma unroll
                for (int j = 0; j < 4; j++) w4v[j] = *(float4*)&wt[(cg + 32 * j) * 68 + k4 * 4];
#pragma unroll
                for (int i = 0; i < 4; i++)
#pragma unroll
                    for (int j = 0; j < 4; j++) {
                        acc[i][j] = fmaf(f4v[i].x, w4v[j].x, acc[i][j]);
                        acc[i][j] = fmaf(f4v[i].y, w4v[j].y, acc[i][j]);
                        acc[i][j] = fmaf(f4v[i].z, w4v[j].z, acc[i][j]);
                        acc[i][j] = fmaf(f4v[i].w, w4v[j].w, acc[i][j]);
                    }
            }
#pragma unroll
            for (int j = 0; j < 4; j++) {
                int c = cg + 32 * j;
                float bc = bias[c];
#pragma unroll
                for (int i = 0; i < 4; i++) {
                    float h = acc[i][j] + bc;
                    sums[j] += h; sqs[j] += h * h;
                    hout[(size_t)(rowbase + rg * 4 + i) * FOUT + c] = __float2bfloat16(h);
                }
            }
        }
        __syncthreads();
        float* suml = fl;
        float* sql  = wt;
#pragma unroll
        for (int j = 0; j < 4; j++) {
            suml[rg * FOUT + cg + 32 * j] = sums[j];
            sql[rg * FOUT + cg + 32 * j]  = sqs[j];
        }
        __syncthreads();
        if (t < FOUT) {
            float S = 0.f, Q = 0.f;
#pragma unroll
            for (int r = 0; r < 16; r++) { S += suml[r * FOUT + t]; Q += sql[r * FOUT + t]; }
            atomicAdd(&gsum[t], S);
            atomicAdd(&gsq[t], Q);
        }
    } else {
        // ---------------- xnorm + bf16 hi/lo split (512 threads, 128 blocks)
        int r = (b - 272) * 512 + t;
        const float4* fr = (const float4*)&feat[(size_t)r * FIN];
        unsigned short hrow[64], lrow[64];
        float s = 0.f;
#pragma unroll
        for (int i = 0; i < 16; i++) {
            float4 v = fr[i];
            s += v.x * v.x + v.y * v.y + v.z * v.z + v.w * v.w;
            float vv[4] = {v.x, v.y, v.z, v.w};
#pragma unroll
            for (int j = 0; j < 4; j++) {
                unsigned short h = bf16_rn(vv[j]);
                float hf = __uint_as_float((unsigned)h << 16);
                hrow[4 * i + j] = h;
                lrow[4 * i + j] = bf16_rn(vv[j] - hf);
            }
        }
        xnorm[r] = s;
#pragma unroll
        for (int i = 0; i < 8; i++) {
            short8 hv, lv;
#pragma unroll
            for (int j = 0; j < 8; j++) { hv[j] = (short)hrow[8 * i + j]; lv[j] = (short)lrow[8 * i + j]; }
            *(short8*)&Xhi[(size_t)r * 64 + 8 * i] = hv;
            *(short8*)&Xlo[(size_t)r * 64 + 8 * i] = lv;
        }
    }
}

// ---------------------------------------------------------------- BN finalize
__global__ void finalize_kernel(const float* __restrict__ gsum, const float* __restrict__ gsq,
        const float* __restrict__ gamma, const float* __restrict__ beta,
        float* __restrict__ acoef, float* __restrict__ ccoef) {
    int c = threadIdx.x;
    float mean = gsum[c] * (1.0f / NN);
    float var  = gsq[c] * (1.0f / NN) - mean * mean;
    float s = rsqrtf(var + 1e-5f) * gamma[c];
    acoef[c] = s;
    ccoef[c] = beta[c] - mean * s;
}

// ---------------------------------------------------------------- KNN filter: MFMA + two-phase threshold
// grid 512: cloud(16) x qgroup(16) x half(2). Wave w owns queries qg*64+w*16..+15 vs 2048 points.
// Phase 1: per (lane,r) stream of 128 points keep 2 smallest scores (unconditional min pair).
// T[q] = 16th smallest of the 32 collected values (32 distinct points => exact d16 <= T).
// Phase 2: re-stream, emit point idx where s <= T+margin into per-query LDS buffer (atomic).
// Margin >> 2x bf16-3pass error => exact-metric top-16 always emitted; refine re-ranks in fp32.
__global__ __launch_bounds__(256, 2) void knn_kernel(
        const unsigned short* __restrict__ Xhi, const unsigned short* __restrict__ Xlo,
        const int* __restrict__ fps_idx, const float* __restrict__ xnorm,
        unsigned short* __restrict__ cand) {
    __shared__ float TL[4][16][32];            // [wave][q][col*2+{0,1}] collected values
    __shared__ float TQ[4][16];                // per-query threshold
    __shared__ int   cntL[4][16];
    __shared__ unsigned short buf[4][16][64];
    const int t = threadIdx.x, b = blockIdx.x;
    const int cloud = b & 15, qg = (b >> 4) & 15, half = b >> 8;
    const int wave = t >> 6, lane = t & 63;
    const int quad = lane >> 4, col = lane & 15;
    const int cbase = cloud * NP;
    const int qloc = qg * 64 + wave * 16;

    // A fragments (loop-invariant): A[m=lane&15][k=quad*8+j]
    const int qrow = fps_idx[cloud * MS + qloc + col];
    const unsigned short* Qh = Xhi + (size_t)(cbase + qrow) * 64;
    const unsigned short* Ql = Xlo + (size_t)(cbase + qrow) * 64;
    short8 Ah0 = *(const short8*)(Qh + quad * 8);
    short8 Ah1 = *(const short8*)(Qh + 32 + quad * 8);
    short8 Al0 = *(const short8*)(Ql + quad * 8);
    short8 Al1 = *(const short8*)(Ql + 32 + quad * 8);

    const int pstart = half * 2048;
    // -------- phase 1: unconditional 2-smallest per (lane, r) stream
    float mA[4] = {INFINITY, INFINITY, INFINITY, INFINITY};
    float mB[4] = {INFINITY, INFINITY, INFINITY, INFINITY};
    for (int tile = 0; tile < 128; tile++) {
        const int prow = cbase + pstart + tile * 16 + col;
        const unsigned short* Bh = Xhi + (size_t)prow * 64;
        const unsigned short* Bl = Xlo + (size_t)prow * 64;
        short8 bh0 = *(const short8*)(Bh + quad * 8);
        short8 bh1 = *(const short8*)(Bh + 32 + quad * 8);
        short8 bl0 = *(const short8*)(Bl + quad * 8);
        short8 bl1 = *(const short8*)(Bl + 32 + quad * 8);
        f32x4 acc = {0.f, 0.f, 0.f, 0.f};
        acc = __builtin_amdgcn_mfma_f32_16x16x32_bf16(Ah0, bh0, acc, 0, 0, 0);
        acc = __builtin_amdgcn_mfma_f32_16x16x32_bf16(Ah1, bh1, acc, 0, 0, 0);
        acc = __builtin_amdgcn_mfma_f32_16x16x32_bf16(Al0, bh0, acc, 0, 0, 0);
        acc = __builtin_amdgcn_mfma_f32_16x16x32_bf16(Al1, bh1, acc, 0, 0, 0);
        acc = __builtin_amdgcn_mfma_f32_16x16x32_bf16(Ah0, bl0, acc, 0, 0, 0);
        acc = __builtin_amdgcn_mfma_f32_16x16x32_bf16(Ah1, bl1, acc, 0, 0, 0);
        float xnv = xnorm[prow];
        // C layout (validated R6/R7): score for query quad*4+r at point pstart+tile*16+col
#pragma unroll
        for (int r = 0; r < 4; r++) {
            float s = fmaf(-2.0f, acc[r], xnv);
            float mx = fmaxf(mA[r], s);
            mA[r] = fminf(mA[r], s);
            mB[r] = fminf(mB[r], mx);
        }
    }
    // -------- threshold: T[q] = 16th smallest of {mA,mB over 16 cols} (wave-local LDS, no barrier)
#pragma unroll
    for (int r = 0; r < 4; r++) {
        TL[wave][quad * 4 + r][col * 2 + 0] = mA[r];
        TL[wave][quad * 4 + r][col * 2 + 1] = mB[r];
    }
    if (lane < 16) cntL[wave][lane] = 0;
    {
        const int q = lane >> 2, j0 = (lane & 3) * 8;
        float v[32];
#pragma unroll
        for (int j = 0; j < 32; j++) v[j] = TL[wave][q][j];
#pragma unroll
        for (int u = 0; u < 8; u++) {
            float vj = TL[wave][q][j0 + u];
            int jj = j0 + u, rank = 0;
#pragma unroll
            for (int k = 0; k < 32; k++)
                rank += (v[k] < vj || (v[k] == vj && k < jj)) ? 1 : 0;
            if (rank == 15) TQ[wave][q] = vj;
        }
    }
    // -------- phase 2: emit candidates below threshold
    float T0 = TQ[wave][quad * 4 + 0] + KNN_MARGIN;
    float T1 = TQ[wave][quad * 4 + 1] + KNN_MARGIN;
    float T2 = TQ[wave][quad * 4 + 2] + KNN_MARGIN;
    float T3 = TQ[wave][quad * 4 + 3] + KNN_MARGIN;
    for (int tile = 0; tile < 128; tile++) {
        const int pidx = pstart + tile * 16 + col;
        const int prow = cbase + pidx;
        const unsigned short* Bh = Xhi + (size_t)prow * 64;
        const unsigned short* Bl = Xlo + (size_t)prow * 64;
        short8 bh0 = *(const short8*)(Bh + quad * 8);
        short8 bh1 = *(const short8*)(Bh + 32 + quad * 8);
        short8 bl0 = *(const short8*)(Bl + quad * 8);
        short8 bl1 = *(const short8*)(Bl + 32 + quad * 8);
        f32x4 acc = {0.f, 0.f, 0.f, 0.f};
        acc = __builtin_amdgcn_mfma_f32_16x16x32_bf16(Ah0, bh0, acc, 0, 0, 0);
        acc = __builtin_amdgcn_mfma_f32_16x16x32_bf16(Ah1, bh1, acc, 0, 0, 0);
        acc = __builtin_amdgcn_mfma_f32_16x16x32_bf16(Al0, bh0, acc, 0, 0, 0);
        acc = __builtin_amdgcn_mfma_f32_16x16x32_bf16(Al1, bh1, acc, 0, 0, 0);
        acc = __builtin_amdgcn_mfma_f32_16x16x32_bf16(Ah0, bl0, acc, 0, 0, 0);
        acc = __builtin_amdgcn_mfma_f32_16x16x32_bf16(Ah1, bl1, acc, 0, 0, 0);
        float xnv = xnorm[prow];
        float s0 = fmaf(-2.0f, acc[0], xnv);
        float s1 = fmaf(-2.0f, acc[1], xnv);
        float s2 = fmaf(-2.0f, acc[2], xnv);
        float s3 = fmaf(-2.0f, acc[3], xnv);
        if (s0 <= T0) { int p = atomicAdd(&cntL[wave][quad * 4 + 0], 1); if (p < 64) buf[wave][quad * 4 + 0][p] = (unsigned short)pidx; }
        if (s1 <= T1) { int p = atomicAdd(&cntL[wave][quad * 4 + 1], 1); if (p < 64) buf[wave][quad * 4 + 1][p] = (unsigned short)pidx; }
        if (s2 <= T2) { int p = atomicAdd(&cntL[wave][quad * 4 + 2], 1); if (p < 64) buf[wave][quad * 4 + 2][p] = (unsigned short)pidx; }
        if (s3 <= T3) { int p = atomicAdd(&cntL[wave][quad * 4 + 3], 1); if (p < 64) buf[wave][quad * 4 + 3][p] = (unsigned short)pidx; }
    }
    // -------- dump (coalesced 128B per query; sentinel-pad)
#pragma unroll
    for (int q = 0; q < 16; q++) {
        int n = cntL[wave][q];
        unsigned short val = (lane < n) ? buf[wave][q][lane] : (unsigned short)0xFFFF;
        cand[(size_t)(cloud * MS + qloc + q) * 128 + half * 64 + lane] = val;
    }
}

// ---------------------------------------------------------------- refine: exact fp32 top-16 + gather/BN/ReLU/maxpool
// block = one query; 128 candidate slots (sentinel-padded), 2 lanes/candidate.
__global__ __launch_bounds__(256) void refine_kernel(
        const float* __restrict__ feat, const int* __restrict__ fps_idx,
        const float* __restrict__ xnorm, const unsigned short* __restrict__ cand,
        const __hip_bfloat16* __restrict__ h, const float* __restrict__ acoef,
        const float* __restrict__ ccoef, float* __restrict__ out_feat) {
    __shared__ float qlds[64];
    __shared__ float cD[128];
    __shared__ int   cI[128];
    __shared__ int   fIdx[16];
    __shared__ float cf[256];
    const int t = threadIdx.x, b = blockIdx.x;
    const int cloud = b & 15, m = b >> 4;          // cloud <-> XCD locality
    const int q = cloud * MS + m;
    const int cbase = cloud * NP;
    if (t < 128) cf[t] = acoef[t]; else cf[t] = ccoef[t - 128];
    if (t < 16) {
        int qr = fps_idx[q];
        float4 v = ((const float4*)(feat + (size_t)(cbase + qr) * FIN))[t];
        *(float4*)&qlds[t * 4] = v;
    }
    __syncthreads();
    // exact fp32 distance: candidate c = t>>1, half jh = t&1 covers 32 dims
    const int c = t >> 1, jh = t & 1;
    const unsigned short cs = cand[(size_t)q * 128 + c];
    const bool valid = (cs != 0xFFFF);
    const int cidx = valid ? (int)cs : 0;
    const float4* xr = (const float4*)(feat + (size_t)(cbase + cidx) * FIN) + jh * 8;
    float a0 = 0.f, a1 = 0.f, a2 = 0.f, a3 = 0.f;
#pragma unroll
    for (int i = 0; i < 8; i++) {
        float4 x4 = xr[i];
        a0 = fmaf(qlds[jh * 32 + 4 * i + 0], x4.x, a0);
        a1 = fmaf(qlds[jh * 32 + 4 * i + 1], x4.y, a1);
        a2 = fmaf(qlds[jh * 32 + 4 * i + 2], x4.z, a2);
        a3 = fmaf(qlds[jh * 32 + 4 * i + 3], x4.w, a3);
    }
    float a = (a0 + a1) + (a2 + a3);
    a += __shfl_xor(a, 1);
    if (jh == 0) {
        cD[c] = valid ? fmaf(-2.0f, a, xnorm[cbase + cidx]) : INFINITY;
        cI[c] = valid ? cidx : (65536 + c);   // distinct tiebreak ids for sentinels
    }
    __syncthreads();
    // rank-count among 128 (lex (d, idx); >=32 real distinct candidates guaranteed)
    if (t < 128) {
        float dv = cD[t]; int iv = cI[t]; int rank = 0;
#pragma unroll 8
        for (int j = 0; j < 128; j++) {
            float dj = cD[j]; int ij = cI[j];
            rank += (dj < dv || (dj == dv && ij < iv)) ? 1 : 0;
        }
        if (rank < 16) fIdx[rank] = iv;
    }
    __syncthreads();
    // gather + BN affine + relu + maxpool
    if (t < 128) {
        const __hip_bfloat16* hb = h + (size_t)cbase * FOUT;
        const float ac = cf[t], cc = cf[128 + t];
        float mx = -INFINITY;
#pragma unroll
        for (int k = 0; k < 16; k++) {
            int row = fIdx[k];
            float hv = __bfloat162float(hb[(size_t)row * FOUT + t]);
            mx = fmaxf(mx, fmaxf(fmaf(ac, hv, cc), 0.f));
        }
        out_feat[(size_t)q * FOUT + t] = mx;
    }
}

// ---------------------------------------------------------------- launch
extern "C" void kernel_launch(void* const* d_in, const int* in_sizes, int n_in,
                              void* d_out, int out_size, void* d_ws, size_t ws_size,
                              hipStream_t stream) {
    (void)in_sizes; (void)n_in; (void)out_size; (void)ws_size;
    const float* position = (const float*)d_in[0];
    const float* features = (const float*)d_in[1];
    const float* W        = (const float*)d_in[3];
    const float* bias     = (const float*)d_in[4];
    const float* gamma    = (const float*)d_in[5];
    const float* beta     = (const float*)d_in[6];
    float* out = (float*)d_out;

    char* ws = (char*)d_ws;
    int*   fps_idx = (int*)ws;                               // 64 KB
    float* gsum    = (float*)(ws + 65536);                   // 512 B
    float* gsq     = (float*)(ws + 66048);                   // 512 B
    float* acoef   = (float*)(ws + 66560);                   // 512 B
    float* ccoef   = (float*)(ws + 67072);                   // 512 B
    float* xnorm   = (float*)(ws + 67584);                   // 256 KB -> ends 329728
    unsigned short* cand = (unsigned short*)(ws + 329728);   // 4 MB   -> ends 4524032
    unsigned short* Xhi  = (unsigned short*)(ws + 4524032);  // 8 MB   -> ends 12912640
    __hip_bfloat16* hbuf = (__hip_bfloat16*)(ws + 12912640); // 16 MB  -> ends ~29.7 MB

    float* out_feat  = out;                 // [16384][128]
    float* out_pos   = out + 2097152;       // [16384][3]
    float* out_batch = out + 2146304;       // [16384]
    // Stash Xlo in the out_feat region (8 MB exact fit); refine overwrites it afterwards.
    unsigned short* Xlo = (unsigned short*)out;

    hipMemsetAsync(gsum, 0, 1024, stream);  // zero gsum+gsq
    front_kernel<<<400, 512, 0, stream>>>(position, features, W, bias,
                                          fps_idx, out_pos, out_batch, xnorm, Xhi, Xlo,
                                          hbuf, gsum, gsq);
    finalize_kernel<<<1, FOUT, 0, stream>>>(gsum, gsq, gamma, beta, acoef, ccoef);
    knn_kernel<<<512, 256, 0, stream>>>(Xhi, Xlo, fps_idx, xnorm, cand);
    refine_kernel<<<16384, 256, 0, stream>>>(features, fps_idx, xnorm, cand,
                                             hbuf, acoef, ccoef, out_feat);
}